// Round 3
// baseline (517.518 us; speedup 1.0000x reference)
//
#include <hip/hip_runtime.h>

// LSTM: B=8192, T=512, IN=8, H=64, OUT=1
// R7 (resubmit; previous round was an infra container failure, no data):
//   two-tile interleave. Each block owns TWO independent 16-batch tiles
//   (BT=32 total), grid 256 = 1 block/CU. Weight/bias regs shared across
//   tiles; per step each wave interleaves two independent
//   {ds_read -> 12 MFMA -> act -> store} streams and ONE barrier serves
//   both tiles (barrier frequency per element halved). R6's x-MFMA hoist
//   reverted (measured -3.6%, chain was not the bottleneck).
// R5: transcendental diet. c kept in scaled domain chat = 2log2e*c:
//   chat' = [chat*(1+A)(1+G) + K(G-1)(1+F)] * rcp((1+F)(1+A)(1+G))
//   h     = (C-1) * rcp((1+O)(1+C)),  C = 2^chat'
//   (A=2^ai_acc, G=2^ag_acc, F=2^af_acc, O=2^ao_acc) -> 5 exp2 + 2 rcp per
//   element. Bias lives in persistent MFMA C-operand regs.
// R4: x staged through double-buffered LDS in 16-step chunks (no inner vmem).
// R2: activation scale folded into weights (-log2e for i/f/o, +2log2e for g).
// Wave w owns hidden units [16w,16w+16). h double-buffered through LDS (f16).
// MFMA layouts (m89/m91/m120 verified):
//   A[m=lane&15][k=(lane>>4)*8+j], B[k=(lane>>4)*8+j][n=lane&15],
//   C/D: col=lane&15, row=(lane>>4)*4+reg.

typedef _Float16 f16_t;
typedef _Float16 half8 __attribute__((ext_vector_type(8)));
typedef __fp16 fp16x2 __attribute__((ext_vector_type(2)));
typedef float floatx2 __attribute__((ext_vector_type(2)));
typedef float floatx4 __attribute__((ext_vector_type(4)));

#define Bn 8192
#define Tn 512
#define INn 8
#define Hn 64
#define BT 16          // rows per sub-tile
#define NT 2           // sub-tiles per block -> 32 batch rows/block
#define CHUNK 16
#define NCHUNK (Tn / CHUNK)
#define HSTRIDE 72    // f16; 36 words -> a0/a1 b128 reads 2-way (free)
#define XTSTRIDE 136  // f16 per tt: 16 rows * 8 + 8 pad; 68 words -> 4-bank skew

__device__ __forceinline__ floatx2 act_pair(float zi0, float zi1,
                                            float zf0, float zf1,
                                            float zg0, float zg1,
                                            float zo0, float zo1,
                                            floatx2& chat) {
  const floatx2 one  = {1.f, 1.f};
  const float  K2   = 2.8853900817779268f;  // 2*log2(e)
  const floatx2 K2v  = {K2, K2};
  const floatx2 mK2v = {-K2, -K2};
  const floatx2 clmp = {126.f, 126.f};
  floatx2 A = {__builtin_amdgcn_exp2f(zi0), __builtin_amdgcn_exp2f(zi1)};
  floatx2 G = {__builtin_amdgcn_exp2f(zg0), __builtin_amdgcn_exp2f(zg1)};
  floatx2 F = {__builtin_amdgcn_exp2f(zf0), __builtin_amdgcn_exp2f(zf1)};
  floatx2 O = {__builtin_amdgcn_exp2f(zo0), __builtin_amdgcn_exp2f(zo1)};
  floatx2 PA  = A + one;
  floatx2 PG  = G + one;
  floatx2 PF  = F + one;
  floatx2 PAG = PA * PG;
  floatx2 num = __builtin_elementwise_fma(G, K2v, mK2v) * PF;  // K(G-1)(1+F)
  floatx2 s   = __builtin_elementwise_fma(chat, PAG, num);
  floatx2 P3  = PF * PAG;
  floatx2 R   = {__builtin_amdgcn_rcpf(P3.x), __builtin_amdgcn_rcpf(P3.y)};
  chat = __builtin_elementwise_min(s * R, clmp);
  floatx2 C2 = {__builtin_amdgcn_exp2f(chat.x), __builtin_amdgcn_exp2f(chat.y)};
  floatx2 P4 = (O + one) * (C2 + one);
  floatx2 Rh = {__builtin_amdgcn_rcpf(P4.x), __builtin_amdgcn_rcpf(P4.y)};
  return (C2 - one) * Rh;  // h = o * tanh(c)
}

__global__ __launch_bounds__(256, 1)
void lstm_fused(const float* __restrict__ xg,
                const float* __restrict__ W_ih,
                const float* __restrict__ W_hh,
                const float* __restrict__ b_ih,
                const float* __restrict__ b_hh,
                const float* __restrict__ W_fc,
                const float* __restrict__ b_fc,
                float* __restrict__ out)
{
  __shared__ alignas(16) f16_t hbuf[NT][2][BT][HSTRIDE];
  __shared__ alignas(16) f16_t xlds[NT][2][CHUNK][XTSTRIDE];

  const int tid   = threadIdx.x;
  const int wv    = tid >> 6;     // wave 0..3 -> hidden units 16w..16w+15
  const int lane  = tid & 63;
  const int n     = lane & 15;    // A-row (batch) / B-col / D-col index
  const int q     = lane >> 4;    // quad
  const int bbase = blockIdx.x * (BT * NT);

  const float LOG2E = 1.4426950408889634f;

  // ---- B fragments (weights), pre-scaled, shared by both tiles.
  // Gate g in {i,f,g,o}: column C = 64*g + 16*wv + n.
  // K layout: k in [0,64) = W_hh cols, [64,72) = W_ih cols, [72,96) = 0.
  half8 bf[4][3];
  #pragma unroll
  for (int g = 0; g < 4; ++g) {
    const float sc = (g == 2) ? (2.f * LOG2E) : (-LOG2E);
    const int C = g * 64 + wv * 16 + n;
    #pragma unroll
    for (int c = 0; c < 3; ++c) {
      half8 v;
      #pragma unroll
      for (int j = 0; j < 8; ++j) {
        const int k = c * 32 + q * 8 + j;
        float w = 0.f;
        if (k < Hn)            w = W_hh[C * Hn + k] * sc;
        else if (k < Hn + INn) w = W_ih[C * INn + (k - Hn)] * sc;
        v[j] = (f16_t)w;
      }
      bf[g][c] = v;
    }
  }

  // ---- scaled biases -> persistent MFMA C-operand registers (shared)
  const int u = wv * 16 + n;  // this lane's hidden unit (acc column)
  const float pb_i = -(b_ih[u]       + b_hh[u])       * LOG2E;
  const float pb_f = -(b_ih[64 + u]  + b_hh[64 + u])  * LOG2E;
  const float pb_g =  (b_ih[128 + u] + b_hh[128 + u]) * (2.f * LOG2E);
  const float pb_o = -(b_ih[192 + u] + b_hh[192 + u]) * LOG2E;
  const floatx4 bi  = {pb_i, pb_i, pb_i, pb_i};
  const floatx4 bfv = {pb_f, pb_f, pb_f, pb_f};
  const floatx4 bg  = {pb_g, pb_g, pb_g, pb_g};
  const floatx4 bo  = {pb_o, pb_o, pb_o, pb_o};

  // ---- LDS init: h0 = 0 (zero everything, cheap one-time)
  for (int i = tid; i < NT * 2 * BT * HSTRIDE; i += 256)
    ((f16_t*)hbuf)[i] = (f16_t)0.f;

  // ---- x staging assignment: lane -> (row, tt); 16-lane groups coalesce 512B
  const int row_s = tid >> 4;   // 0..15 batch row within sub-tile
  const int tt_s  = tid & 15;   // 0..15 timestep within chunk
  const float* xps0 = xg + ((size_t)(bbase + row_s) * Tn + tt_s) * INn;
  const float* xps1 = xps0 + (size_t)BT * Tn * INn;

  // preload chunk 0 into registers (both tiles)
  float4 pa0 = *(const float4*)(xps0);
  float4 pb0 = *(const float4*)(xps0 + 4);
  float4 pa1 = *(const float4*)(xps1);
  float4 pb1 = *(const float4*)(xps1 + 4);

  floatx2 chat01_0 = {0.f, 0.f};  // tile0, rows q*4+{0,1}
  floatx2 chat23_0 = {0.f, 0.f};  // tile0, rows q*4+{2,3}
  floatx2 chat01_1 = {0.f, 0.f};  // tile1
  floatx2 chat23_1 = {0.f, 0.f};

  for (int ch = 0; ch < NCHUNK; ++ch) {
    // ---- write staged chunk to LDS (f16), both tiles
    {
      union { half8 v; fp16x2 h2[4]; } P;
      P.h2[0] = __builtin_amdgcn_cvt_pkrtz(pa0.x, pa0.y);
      P.h2[1] = __builtin_amdgcn_cvt_pkrtz(pa0.z, pa0.w);
      P.h2[2] = __builtin_amdgcn_cvt_pkrtz(pb0.x, pb0.y);
      P.h2[3] = __builtin_amdgcn_cvt_pkrtz(pb0.z, pb0.w);
      *(half8*)&xlds[0][ch & 1][tt_s][row_s * 8] = P.v;
      P.h2[0] = __builtin_amdgcn_cvt_pkrtz(pa1.x, pa1.y);
      P.h2[1] = __builtin_amdgcn_cvt_pkrtz(pa1.z, pa1.w);
      P.h2[2] = __builtin_amdgcn_cvt_pkrtz(pb1.x, pb1.y);
      P.h2[3] = __builtin_amdgcn_cvt_pkrtz(pb1.z, pb1.w);
      *(half8*)&xlds[1][ch & 1][tt_s][row_s * 8] = P.v;
    }
    __syncthreads();  // xlds chunk + (first iter) hbuf zero visible

    // ---- prefetch next chunk (uniform clamp; latency hidden over 16 steps)
    const int chn = (ch + 1 < NCHUNK) ? (ch + 1) : 0;
    pa0 = *(const float4*)(xps0 + (size_t)chn * CHUNK * INn);
    pb0 = *(const float4*)(xps0 + (size_t)chn * CHUNK * INn + 4);
    pa1 = *(const float4*)(xps1 + (size_t)chn * CHUNK * INn);
    pb1 = *(const float4*)(xps1 + (size_t)chn * CHUNK * INn + 4);

    #pragma unroll
    for (int tt = 0; tt < CHUNK; ++tt) {
      const int p  = tt & 1;
      const int pn = p ^ 1;

      // A fragments for both tiles
      const half8 a00 = *(const half8*)&hbuf[0][p][n][q * 8];
      const half8 a01 = *(const half8*)&hbuf[0][p][n][32 + q * 8];
      const half8 a02 = *(const half8*)&xlds[0][ch & 1][tt][n * 8];
      const half8 a10 = *(const half8*)&hbuf[1][p][n][q * 8];
      const half8 a11 = *(const half8*)&hbuf[1][p][n][32 + q * 8];
      const half8 a12 = *(const half8*)&xlds[1][ch & 1][tt][n * 8];

      // tile0 gates (bias regs as first-MFMA C operand)
      floatx4 ai0 = __builtin_amdgcn_mfma_f32_16x16x32_f16(a00, bf[0][0], bi,  0, 0, 0);
      floatx4 af0 = __builtin_amdgcn_mfma_f32_16x16x32_f16(a00, bf[1][0], bfv, 0, 0, 0);
      floatx4 ag0 = __builtin_amdgcn_mfma_f32_16x16x32_f16(a00, bf[2][0], bg,  0, 0, 0);
      floatx4 ao0 = __builtin_amdgcn_mfma_f32_16x16x32_f16(a00, bf[3][0], bo,  0, 0, 0);
      // tile1 gates
      floatx4 ai1 = __builtin_amdgcn_mfma_f32_16x16x32_f16(a10, bf[0][0], bi,  0, 0, 0);
      floatx4 af1 = __builtin_amdgcn_mfma_f32_16x16x32_f16(a10, bf[1][0], bfv, 0, 0, 0);
      floatx4 ag1 = __builtin_amdgcn_mfma_f32_16x16x32_f16(a10, bf[2][0], bg,  0, 0, 0);
      floatx4 ao1 = __builtin_amdgcn_mfma_f32_16x16x32_f16(a10, bf[3][0], bo,  0, 0, 0);

      ai0 = __builtin_amdgcn_mfma_f32_16x16x32_f16(a01, bf[0][1], ai0, 0, 0, 0);
      af0 = __builtin_amdgcn_mfma_f32_16x16x32_f16(a01, bf[1][1], af0, 0, 0, 0);
      ag0 = __builtin_amdgcn_mfma_f32_16x16x32_f16(a01, bf[2][1], ag0, 0, 0, 0);
      ao0 = __builtin_amdgcn_mfma_f32_16x16x32_f16(a01, bf[3][1], ao0, 0, 0, 0);
      ai1 = __builtin_amdgcn_mfma_f32_16x16x32_f16(a11, bf[0][1], ai1, 0, 0, 0);
      af1 = __builtin_amdgcn_mfma_f32_16x16x32_f16(a11, bf[1][1], af1, 0, 0, 0);
      ag1 = __builtin_amdgcn_mfma_f32_16x16x32_f16(a11, bf[2][1], ag1, 0, 0, 0);
      ao1 = __builtin_amdgcn_mfma_f32_16x16x32_f16(a11, bf[3][1], ao1, 0, 0, 0);

      ai0 = __builtin_amdgcn_mfma_f32_16x16x32_f16(a02, bf[0][2], ai0, 0, 0, 0);
      af0 = __builtin_amdgcn_mfma_f32_16x16x32_f16(a02, bf[1][2], af0, 0, 0, 0);
      ag0 = __builtin_amdgcn_mfma_f32_16x16x32_f16(a02, bf[2][2], ag0, 0, 0, 0);
      ao0 = __builtin_amdgcn_mfma_f32_16x16x32_f16(a02, bf[3][2], ao0, 0, 0, 0);
      ai1 = __builtin_amdgcn_mfma_f32_16x16x32_f16(a12, bf[0][2], ai1, 0, 0, 0);
      af1 = __builtin_amdgcn_mfma_f32_16x16x32_f16(a12, bf[1][2], af1, 0, 0, 0);
      ag1 = __builtin_amdgcn_mfma_f32_16x16x32_f16(a12, bf[2][2], ag1, 0, 0, 0);
      ao1 = __builtin_amdgcn_mfma_f32_16x16x32_f16(a12, bf[3][2], ao1, 0, 0, 0);

      // activations: 4 independent act_pair streams (2 per tile)
      const floatx2 h01_0 = act_pair(ai0[0], ai0[1], af0[0], af0[1],
                                     ag0[0], ag0[1], ao0[0], ao0[1], chat01_0);
      hbuf[0][pn][q * 4 + 0][u] = (f16_t)h01_0.x;
      hbuf[0][pn][q * 4 + 1][u] = (f16_t)h01_0.y;
      const floatx2 h23_0 = act_pair(ai0[2], ai0[3], af0[2], af0[3],
                                     ag0[2], ag0[3], ao0[2], ao0[3], chat23_0);
      hbuf[0][pn][q * 4 + 2][u] = (f16_t)h23_0.x;
      hbuf[0][pn][q * 4 + 3][u] = (f16_t)h23_0.y;
      const floatx2 h01_1 = act_pair(ai1[0], ai1[1], af1[0], af1[1],
                                     ag1[0], ag1[1], ao1[0], ao1[1], chat01_1);
      hbuf[1][pn][q * 4 + 0][u] = (f16_t)h01_1.x;
      hbuf[1][pn][q * 4 + 1][u] = (f16_t)h01_1.y;
      const floatx2 h23_1 = act_pair(ai1[2], ai1[3], af1[2], af1[3],
                                     ag1[2], ag1[3], ao1[2], ao1[3], chat23_1);
      hbuf[1][pn][q * 4 + 2][u] = (f16_t)h23_1.x;
      hbuf[1][pn][q * 4 + 3][u] = (f16_t)h23_1.y;

      __syncthreads();  // one barrier serves both tiles
    }
  }

  // ---- epilogue: out[b] = h_T[b,:] . W_fc + b_fc  (h_T in parity 0)
  if (wv < NT) {
    const int tile = wv;
    const int b = lane & 15;
    const int part = lane >> 4;
    float s = 0.f;
    #pragma unroll
    for (int k = 0; k < 16; ++k) {
      const int uu = part * 16 + k;
      s = __builtin_fmaf((float)hbuf[tile][0][b][uu], W_fc[uu], s);
    }
    s += __shfl_down(s, 32);
    s += __shfl_down(s, 16);
    if (lane < 16) out[bbase + tile * BT + b] = s + b_fc[0];
  }
}

extern "C" void kernel_launch(void* const* d_in, const int* in_sizes, int n_in,
                              void* d_out, int out_size, void* d_ws, size_t ws_size,
                              hipStream_t stream) {
  const float* x    = (const float*)d_in[0];
  const float* W_ih = (const float*)d_in[1];
  const float* W_hh = (const float*)d_in[2];
  const float* b_ih = (const float*)d_in[3];
  const float* b_hh = (const float*)d_in[4];
  const float* W_fc = (const float*)d_in[5];
  const float* b_fc = (const float*)d_in[6];
  float* out = (float*)d_out;
  dim3 grid(Bn / (BT * NT)), block(256);
  hipLaunchKernelGGL(lstm_fused, grid, block, 0, stream,
                     x, W_ih, W_hh, b_ih, b_hh, W_fc, b_fc, out);
}

// Round 4
// 445.991 us; speedup vs baseline: 1.1604x; 1.1604x over previous
//
#include <hip/hip_runtime.h>

// LSTM: B=8192, T=512, IN=8, H=64, OUT=1
// R8: revert to R5 topology (BT=16, grid 512, 2 blocks/CU — R7's 1-block/CU
//   fat-wave variant measured -31%: single wave can't overlap its own MFMA
//   with its own dependent VALU; need 2 phase-shifted barrier groups/CU).
//   On top of R5:
//   - transposed MFMA orientation: A=weights, B=h/x. Same hbuf layout and
//     same ds_reads; D rows become units -> h writeback is 2 cvt_pkrtz +
//     one ds_write_b64 (was 4 scattered b16 + 4 cvt). Bias seed per-lane f4.
//   - x-term MFMA shrunk to 16x16x16 (K=16, 8 real) instead of 16x16x32
//     (K=32, 8 real): ~half the MFMA cycles on the wasted third MFMA.
//     x staged in [tt][batch][24] f16 rows, upper half pre-zeroed.
// R5: transcendental diet. c kept in scaled domain chat = 2log2e*c:
//   chat' = [chat*(1+A)(1+G) + K(G-1)(1+F)] * rcp((1+F)(1+A)(1+G))
//   h     = (C-1) * rcp((1+O)(1+C)),  C = 2^chat'
//   5 exp2 + 2 rcp per element. Bias in persistent MFMA C-operand regs.
// R4: x staged through double-buffered LDS in 16-step chunks (no inner vmem).
// R2: activation scale folded into weights (-log2e for i/f/o, +2log2e for g).
// Wave w owns hidden units [16w,16w+16). h double-buffered through LDS (f16).
// MFMA layouts (m89/m91/m120 verified):
//   A[m=lane&15][k=(lane>>4)*8+j] (x32) / [k=(lane>>4)*4+j] (x16),
//   B[k][n=lane&15], C/D: col=lane&15, row=(lane>>4)*4+reg.

typedef _Float16 f16_t;
typedef _Float16 half8 __attribute__((ext_vector_type(8)));
typedef _Float16 half4 __attribute__((ext_vector_type(4)));
typedef __fp16 fp16x2 __attribute__((ext_vector_type(2)));
typedef float floatx2 __attribute__((ext_vector_type(2)));
typedef float floatx4 __attribute__((ext_vector_type(4)));

#define Bn 8192
#define Tn 512
#define INn 8
#define Hn 64
#define BT 16
#define CHUNK 16
#define NCHUNK (Tn / CHUNK)
#define HSTRIDE 72   // f16; row = 144B: b128 reads 16B-aligned, 2-way banks (free)
#define XROW 24      // f16 per batch row: 8 real + 8 zero + 8 pad; 48B, 16B-aligned

__device__ __forceinline__ floatx2 act_pair(float zi0, float zi1,
                                            float zf0, float zf1,
                                            float zg0, float zg1,
                                            float zo0, float zo1,
                                            floatx2& chat) {
  const floatx2 one  = {1.f, 1.f};
  const float  K2   = 2.8853900817779268f;  // 2*log2(e)
  const floatx2 K2v  = {K2, K2};
  const floatx2 mK2v = {-K2, -K2};
  const floatx2 clmp = {126.f, 126.f};
  floatx2 A = {__builtin_amdgcn_exp2f(zi0), __builtin_amdgcn_exp2f(zi1)};
  floatx2 G = {__builtin_amdgcn_exp2f(zg0), __builtin_amdgcn_exp2f(zg1)};
  floatx2 F = {__builtin_amdgcn_exp2f(zf0), __builtin_amdgcn_exp2f(zf1)};
  floatx2 O = {__builtin_amdgcn_exp2f(zo0), __builtin_amdgcn_exp2f(zo1)};
  floatx2 PA  = A + one;
  floatx2 PG  = G + one;
  floatx2 PF  = F + one;
  floatx2 PAG = PA * PG;
  floatx2 num = __builtin_elementwise_fma(G, K2v, mK2v) * PF;  // K(G-1)(1+F)
  floatx2 s   = __builtin_elementwise_fma(chat, PAG, num);
  floatx2 P3  = PF * PAG;
  floatx2 R   = {__builtin_amdgcn_rcpf(P3.x), __builtin_amdgcn_rcpf(P3.y)};
  chat = __builtin_elementwise_min(s * R, clmp);
  floatx2 C2 = {__builtin_amdgcn_exp2f(chat.x), __builtin_amdgcn_exp2f(chat.y)};
  floatx2 P4 = (O + one) * (C2 + one);
  floatx2 Rh = {__builtin_amdgcn_rcpf(P4.x), __builtin_amdgcn_rcpf(P4.y)};
  return (C2 - one) * Rh;  // h = o * tanh(c)
}

__global__ __launch_bounds__(256, 2)
void lstm_fused(const float* __restrict__ xg,
                const float* __restrict__ W_ih,
                const float* __restrict__ W_hh,
                const float* __restrict__ b_ih,
                const float* __restrict__ b_hh,
                const float* __restrict__ W_fc,
                const float* __restrict__ b_fc,
                float* __restrict__ out)
{
  __shared__ alignas(16) f16_t hbuf[2][BT][HSTRIDE];          // [batch][unit]
  __shared__ alignas(16) f16_t xlds[2][CHUNK][BT][XROW];      // [tt][batch][feat]

  const int tid   = threadIdx.x;
  const int wv    = tid >> 6;     // wave 0..3 -> hidden units 16w..16w+15
  const int lane  = tid & 63;
  const int n     = lane & 15;    // A-row (unit) for weights / B-col (batch) / D-col
  const int q     = lane >> 4;    // quad
  const int bbase = blockIdx.x * BT;

  const float LOG2E = 1.4426950408889634f;

  // ---- weight A-fragments, pre-scaled, resident in VGPRs.
  // Gate g: weight row (unit) U = 64*g-local; this wave covers units
  // wv*16 + m, m = lane&15 = n. x32 frags cover k in [0,64) of W_hh;
  // x16 frag covers k in [0,16): [0,8)=W_ih, [8,16)=0.
  half8 bf[4][2];
  half4 bfx[4];
  #pragma unroll
  for (int g = 0; g < 4; ++g) {
    const float sc = (g == 2) ? (2.f * LOG2E) : (-LOG2E);
    const int C = g * 64 + wv * 16 + n;   // global gate-unit row
    #pragma unroll
    for (int c = 0; c < 2; ++c) {
      half8 v;
      #pragma unroll
      for (int j = 0; j < 8; ++j) {
        const int k = c * 32 + q * 8 + j;          // < 64 always
        v[j] = (f16_t)(W_hh[C * Hn + k] * sc);
      }
      bf[g][c] = v;
    }
    half4 vx;
    #pragma unroll
    for (int j = 0; j < 4; ++j) {
      const int k = q * 4 + j;                     // [0,16)
      vx[j] = (f16_t)((k < INn) ? (W_ih[C * INn + k] * sc) : 0.f);
    }
    bfx[g] = vx;
  }

  // ---- scaled biases -> persistent MFMA C-operand registers.
  // D rows = units: lane covers units u0..u0+3.
  const int u0 = wv * 16 + q * 4;
  floatx4 bi, bfv, bg, bo;
  #pragma unroll
  for (int r = 0; r < 4; ++r) {
    const int uu = u0 + r;
    bi[r]  = -(b_ih[uu]        + b_hh[uu])        * LOG2E;
    bfv[r] = -(b_ih[64 + uu]   + b_hh[64 + uu])   * LOG2E;
    bg[r]  =  (b_ih[128 + uu]  + b_hh[128 + uu])  * (2.f * LOG2E);
    bo[r]  = -(b_ih[192 + uu]  + b_hh[192 + uu])  * LOG2E;
  }

  // ---- LDS init: h0 = 0 in hbuf[0]; all of xlds = 0 (zero k-tail persists)
  for (int i = tid; i < BT * HSTRIDE; i += 256) ((f16_t*)hbuf[0])[i] = (f16_t)0.f;
  for (int i = tid; i < 2 * CHUNK * BT * XROW; i += 256) ((f16_t*)xlds)[i] = (f16_t)0.f;
  __syncthreads();  // init visible before staging overwrites the low halves

  // ---- x staging assignment: lane -> (row, tt); 16-lane groups coalesce 512B
  const int row_s = tid >> 4;   // 0..15 batch row
  const int tt_s  = tid & 15;   // 0..15 timestep within chunk
  const float* xps = xg + ((size_t)(bbase + row_s) * Tn + tt_s) * INn;

  // preload chunk 0 into registers
  float4 pa = *(const float4*)(xps);
  float4 pb2 = *(const float4*)(xps + 4);

  floatx2 chat01 = {0.f, 0.f};  // scaled cell state, units u0+{0,1}
  floatx2 chat23 = {0.f, 0.f};  // units u0+{2,3}

  for (int ch = 0; ch < NCHUNK; ++ch) {
    // ---- write staged chunk to LDS (f16): 8 real features per row
    union { half8 v; fp16x2 h2[4]; } P;
    P.h2[0] = __builtin_amdgcn_cvt_pkrtz(pa.x, pa.y);
    P.h2[1] = __builtin_amdgcn_cvt_pkrtz(pa.z, pa.w);
    P.h2[2] = __builtin_amdgcn_cvt_pkrtz(pb2.x, pb2.y);
    P.h2[3] = __builtin_amdgcn_cvt_pkrtz(pb2.z, pb2.w);
    *(half8*)&xlds[ch & 1][tt_s][row_s][0] = P.v;
    __syncthreads();  // xlds chunk visible

    // ---- prefetch next chunk (uniform clamp; latency hidden over 16 steps)
    const int chn = (ch + 1 < NCHUNK) ? (ch + 1) : 0;
    pa  = *(const float4*)(xps + (size_t)chn * CHUNK * INn);
    pb2 = *(const float4*)(xps + (size_t)chn * CHUNK * INn + 4);

    #pragma unroll
    for (int tt = 0; tt < CHUNK; ++tt) {
      const int p  = tt & 1;
      const int pn = p ^ 1;

      // B fragments: h chunks from LDS (k = unit), x fragment (k = feature)
      const half8 b0 = *(const half8*)&hbuf[p][n][q * 8];
      const half8 b1 = *(const half8*)&hbuf[p][n][32 + q * 8];
      const half4 bx = *(const half4*)&xlds[ch & 1][tt][n][q * 4];

      // D = W * h(+x) + bias; bias regs as first-MFMA C operand
      floatx4 ai = __builtin_amdgcn_mfma_f32_16x16x32_f16(bf[0][0], b0, bi,  0, 0, 0);
      floatx4 af = __builtin_amdgcn_mfma_f32_16x16x32_f16(bf[1][0], b0, bfv, 0, 0, 0);
      floatx4 ag = __builtin_amdgcn_mfma_f32_16x16x32_f16(bf[2][0], b0, bg,  0, 0, 0);
      floatx4 ao = __builtin_amdgcn_mfma_f32_16x16x32_f16(bf[3][0], b0, bo,  0, 0, 0);
      ai = __builtin_amdgcn_mfma_f32_16x16x32_f16(bf[0][1], b1, ai, 0, 0, 0);
      af = __builtin_amdgcn_mfma_f32_16x16x32_f16(bf[1][1], b1, af, 0, 0, 0);
      ag = __builtin_amdgcn_mfma_f32_16x16x32_f16(bf[2][1], b1, ag, 0, 0, 0);
      ao = __builtin_amdgcn_mfma_f32_16x16x32_f16(bf[3][1], b1, ao, 0, 0, 0);
      ai = __builtin_amdgcn_mfma_f32_16x16x16f16(bfx[0], bx, ai, 0, 0, 0);
      af = __builtin_amdgcn_mfma_f32_16x16x16f16(bfx[1], bx, af, 0, 0, 0);
      ag = __builtin_amdgcn_mfma_f32_16x16x16f16(bfx[2], bx, ag, 0, 0, 0);
      ao = __builtin_amdgcn_mfma_f32_16x16x16f16(bfx[3], bx, ao, 0, 0, 0);

      // activations: lane's 4 elements = units u0+0..3, batch n
      const floatx2 h01 = act_pair(ai[0], ai[1], af[0], af[1],
                                   ag[0], ag[1], ao[0], ao[1], chat01);
      const floatx2 h23 = act_pair(ai[2], ai[3], af[2], af[3],
                                   ag[2], ag[3], ao[2], ao[3], chat23);

      // packed writeback: 4 consecutive units of batch n -> one b64
      union { half4 v; fp16x2 h2[2]; } Wq;
      Wq.h2[0] = __builtin_amdgcn_cvt_pkrtz(h01.x, h01.y);
      Wq.h2[1] = __builtin_amdgcn_cvt_pkrtz(h23.x, h23.y);
      *(half4*)&hbuf[pn][n][u0] = Wq.v;

      __syncthreads();
    }
  }

  // ---- epilogue: out[b] = h_T[b,:] . W_fc + b_fc   (h_T is in hbuf[0])
  if (tid < 64) {
    const int b = lane & 15;
    const int part = lane >> 4;
    float s = 0.f;
    #pragma unroll
    for (int k = 0; k < 16; ++k) {
      const int uu = part * 16 + k;
      s = __builtin_fmaf((float)hbuf[0][b][uu], W_fc[uu], s);
    }
    s += __shfl_down(s, 32);
    s += __shfl_down(s, 16);
    if (lane < 16) out[bbase + b] = s + b_fc[0];
  }
}

extern "C" void kernel_launch(void* const* d_in, const int* in_sizes, int n_in,
                              void* d_out, int out_size, void* d_ws, size_t ws_size,
                              hipStream_t stream) {
  const float* x    = (const float*)d_in[0];
  const float* W_ih = (const float*)d_in[1];
  const float* W_hh = (const float*)d_in[2];
  const float* b_ih = (const float*)d_in[3];
  const float* b_hh = (const float*)d_in[4];
  const float* W_fc = (const float*)d_in[5];
  const float* b_fc = (const float*)d_in[6];
  float* out = (float*)d_out;
  dim3 grid(Bn / BT), block(256);
  hipLaunchKernelGGL(lstm_fused, grid, block, 0, stream,
                     x, W_ih, W_hh, b_ih, b_hh, W_fc, b_fc, out);
}

// Round 5
// 437.166 us; speedup vs baseline: 1.1838x; 1.0202x over previous
//
#include <hip/hip_runtime.h>

// LSTM: B=8192, T=512, IN=8, H=64, OUT=1
// R9 (on R8): critical-path/barrier diet.
//   - chunk-top barrier removed (16 barriers/chunk, was 17): staging write
//     (opposite xlds parity) folded into tt==0 body; regular step barrier
//     publishes it. Global prefetch of chunk ch+2 reissued at tt==1.
//   - x fragments chunk-preloaded to regs (16 x half4): per-step x ds_read
//     eliminated from the post-barrier critical path.
//   - s_setprio(1) around the MFMA cluster (T5): the 2 resident blocks/CU
//     are phase-shifted; favor the MFMA-entering wave.
// R8: transposed MFMA orientation (A=weights, B=h/x): packed b64 h-writeback;
//   x-term as 16x16x16 MFMA (K=16, 8 real) instead of x32. 339.6 us.
// R7 (reverted): 1 block/CU fat waves = -31%. Need 2 phase-shifted blocks/CU.
// R5: transcendental diet. c kept in scaled domain chat = 2log2e*c:
//   chat' = [chat*(1+A)(1+G) + K(G-1)(1+F)] * rcp((1+F)(1+A)(1+G))
//   h     = (C-1) * rcp((1+O)(1+C)),  C = 2^chat'
//   5 exp2 + 2 rcp per element. Bias in persistent MFMA C-operand regs.
// R4: x staged through double-buffered LDS in 16-step chunks (no inner vmem).
// R2: activation scale folded into weights (-log2e for i/f/o, +2log2e for g).
// MFMA layouts (m89/m91/m120 verified):
//   A[m=lane&15][k=(lane>>4)*8+j] (x32) / [k=(lane>>4)*4+j] (x16),
//   B[k][n=lane&15], C/D: col=lane&15, row=(lane>>4)*4+reg.

typedef _Float16 f16_t;
typedef _Float16 half8 __attribute__((ext_vector_type(8)));
typedef _Float16 half4 __attribute__((ext_vector_type(4)));
typedef __fp16 fp16x2 __attribute__((ext_vector_type(2)));
typedef float floatx2 __attribute__((ext_vector_type(2)));
typedef float floatx4 __attribute__((ext_vector_type(4)));

#define Bn 8192
#define Tn 512
#define INn 8
#define Hn 64
#define BT 16
#define CHUNK 16
#define NCHUNK (Tn / CHUNK)
#define HSTRIDE 72   // f16; row = 144B: b128 reads 16B-aligned, 2-way banks (free)
#define XROW 24      // f16 per batch row: 8 real + 8 zero + 8 pad; 48B, 16B-aligned

__device__ __forceinline__ floatx2 act_pair(float zi0, float zi1,
                                            float zf0, float zf1,
                                            float zg0, float zg1,
                                            float zo0, float zo1,
                                            floatx2& chat) {
  const floatx2 one  = {1.f, 1.f};
  const float  K2   = 2.8853900817779268f;  // 2*log2(e)
  const floatx2 K2v  = {K2, K2};
  const floatx2 mK2v = {-K2, -K2};
  const floatx2 clmp = {126.f, 126.f};
  floatx2 A = {__builtin_amdgcn_exp2f(zi0), __builtin_amdgcn_exp2f(zi1)};
  floatx2 G = {__builtin_amdgcn_exp2f(zg0), __builtin_amdgcn_exp2f(zg1)};
  floatx2 F = {__builtin_amdgcn_exp2f(zf0), __builtin_amdgcn_exp2f(zf1)};
  floatx2 O = {__builtin_amdgcn_exp2f(zo0), __builtin_amdgcn_exp2f(zo1)};
  floatx2 PA  = A + one;
  floatx2 PG  = G + one;
  floatx2 PF  = F + one;
  floatx2 PAG = PA * PG;
  floatx2 num = __builtin_elementwise_fma(G, K2v, mK2v) * PF;  // K(G-1)(1+F)
  floatx2 s   = __builtin_elementwise_fma(chat, PAG, num);
  floatx2 P3  = PF * PAG;
  floatx2 R   = {__builtin_amdgcn_rcpf(P3.x), __builtin_amdgcn_rcpf(P3.y)};
  chat = __builtin_elementwise_min(s * R, clmp);
  floatx2 C2 = {__builtin_amdgcn_exp2f(chat.x), __builtin_amdgcn_exp2f(chat.y)};
  floatx2 P4 = (O + one) * (C2 + one);
  floatx2 Rh = {__builtin_amdgcn_rcpf(P4.x), __builtin_amdgcn_rcpf(P4.y)};
  return (C2 - one) * Rh;  // h = o * tanh(c)
}

__global__ __launch_bounds__(256, 2)
void lstm_fused(const float* __restrict__ xg,
                const float* __restrict__ W_ih,
                const float* __restrict__ W_hh,
                const float* __restrict__ b_ih,
                const float* __restrict__ b_hh,
                const float* __restrict__ W_fc,
                const float* __restrict__ b_fc,
                float* __restrict__ out)
{
  __shared__ alignas(16) f16_t hbuf[2][BT][HSTRIDE];          // [batch][unit]
  __shared__ alignas(16) f16_t xlds[2][CHUNK][BT][XROW];      // [tt][batch][feat]

  const int tid   = threadIdx.x;
  const int wv    = tid >> 6;     // wave 0..3 -> hidden units 16w..16w+15
  const int lane  = tid & 63;
  const int n     = lane & 15;    // A-row (unit) / B-col (batch) / D-col
  const int q     = lane >> 4;    // quad
  const int bbase = blockIdx.x * BT;

  const float LOG2E = 1.4426950408889634f;

  // ---- weight A-fragments, pre-scaled, resident in VGPRs.
  half8 bf[4][2];
  half4 bfx[4];
  #pragma unroll
  for (int g = 0; g < 4; ++g) {
    const float sc = (g == 2) ? (2.f * LOG2E) : (-LOG2E);
    const int C = g * 64 + wv * 16 + n;   // global gate-unit row
    #pragma unroll
    for (int c = 0; c < 2; ++c) {
      half8 v;
      #pragma unroll
      for (int j = 0; j < 8; ++j) {
        const int k = c * 32 + q * 8 + j;          // < 64 always
        v[j] = (f16_t)(W_hh[C * Hn + k] * sc);
      }
      bf[g][c] = v;
    }
    half4 vx;
    #pragma unroll
    for (int j = 0; j < 4; ++j) {
      const int k = q * 4 + j;                     // [0,16)
      vx[j] = (f16_t)((k < INn) ? (W_ih[C * INn + k] * sc) : 0.f);
    }
    bfx[g] = vx;
  }

  // ---- scaled biases -> persistent MFMA C-operand registers.
  const int u0 = wv * 16 + q * 4;   // lane covers units u0..u0+3
  floatx4 bi, bfv, bg, bo;
  #pragma unroll
  for (int r = 0; r < 4; ++r) {
    const int uu = u0 + r;
    bi[r]  = -(b_ih[uu]        + b_hh[uu])        * LOG2E;
    bfv[r] = -(b_ih[64 + uu]   + b_hh[64 + uu])   * LOG2E;
    bg[r]  =  (b_ih[128 + uu]  + b_hh[128 + uu])  * (2.f * LOG2E);
    bo[r]  = -(b_ih[192 + uu]  + b_hh[192 + uu])  * LOG2E;
  }

  // ---- x staging assignment: lane -> (row, tt); 16-lane groups coalesce 512B
  const int row_s = tid >> 4;   // 0..15 batch row
  const int tt_s  = tid & 15;   // 0..15 timestep within chunk
  const float* xps = xg + ((size_t)(bbase + row_s) * Tn + tt_s) * INn;

  // ---- one-time LDS init (all writes disjoint -> single barrier):
  //   hbuf[0] = 0; x k-tails [8..24) = 0 (both parities); chunk 0 -> xlds[0]
  for (int i = tid; i < BT * HSTRIDE; i += 256) ((f16_t*)hbuf[0])[i] = (f16_t)0.f;
  {
    const half8 z = {};
    #pragma unroll
    for (int r = tid; r < 2 * CHUNK * BT; r += 256) {
      f16_t* base = &xlds[r >> 8][(r >> 4) & 15][r & 15][0];
      *(half8*)(base + 8)  = z;
      *(half8*)(base + 16) = z;
    }
  }
  {
    float4 a  = *(const float4*)(xps);
    float4 b2 = *(const float4*)(xps + 4);
    union { half8 v; fp16x2 h2[4]; } P;
    P.h2[0] = __builtin_amdgcn_cvt_pkrtz(a.x, a.y);
    P.h2[1] = __builtin_amdgcn_cvt_pkrtz(a.z, a.w);
    P.h2[2] = __builtin_amdgcn_cvt_pkrtz(b2.x, b2.y);
    P.h2[3] = __builtin_amdgcn_cvt_pkrtz(b2.z, b2.w);
    *(half8*)&xlds[0][tt_s][row_s][0] = P.v;
  }
  // preload chunk 1 into registers (written to LDS at ch=0, tt=0)
  float4 pa  = *(const float4*)(xps + CHUNK * INn);
  float4 pb2 = *(const float4*)(xps + CHUNK * INn + 4);

  __syncthreads();  // hbuf zero + x tails + chunk 0 visible

  floatx2 chat01 = {0.f, 0.f};  // scaled cell state, units u0+{0,1}
  floatx2 chat23 = {0.f, 0.f};  // units u0+{2,3}

  for (int ch = 0; ch < NCHUNK; ++ch) {
    // ---- chunk-top (no barrier): preload this chunk's 16 x fragments.
    // xlds[ch&1] was published by prev chunk's tt=15 barrier (ch=0: init).
    half4 bx[CHUNK];
    #pragma unroll
    for (int t = 0; t < CHUNK; ++t)
      bx[t] = *(const half4*)&xlds[ch & 1][t][n][q * 4];

    #pragma unroll
    for (int tt = 0; tt < CHUNK; ++tt) {
      const int p  = tt & 1;
      const int pn = p ^ 1;

      // post-barrier critical chain: h fragments only
      const half8 b0 = *(const half8*)&hbuf[p][n][q * 8];
      const half8 b1 = *(const half8*)&hbuf[p][n][32 + q * 8];

      __builtin_amdgcn_s_setprio(1);
      // D = W * (h|x) + bias; bias regs as first-MFMA C operand
      floatx4 ai = __builtin_amdgcn_mfma_f32_16x16x32_f16(bf[0][0], b0, bi,  0, 0, 0);
      floatx4 af = __builtin_amdgcn_mfma_f32_16x16x32_f16(bf[1][0], b0, bfv, 0, 0, 0);
      floatx4 ag = __builtin_amdgcn_mfma_f32_16x16x32_f16(bf[2][0], b0, bg,  0, 0, 0);
      floatx4 ao = __builtin_amdgcn_mfma_f32_16x16x32_f16(bf[3][0], b0, bo,  0, 0, 0);
      ai = __builtin_amdgcn_mfma_f32_16x16x32_f16(bf[0][1], b1, ai, 0, 0, 0);
      af = __builtin_amdgcn_mfma_f32_16x16x32_f16(bf[1][1], b1, af, 0, 0, 0);
      ag = __builtin_amdgcn_mfma_f32_16x16x32_f16(bf[2][1], b1, ag, 0, 0, 0);
      ao = __builtin_amdgcn_mfma_f32_16x16x32_f16(bf[3][1], b1, ao, 0, 0, 0);
      ai = __builtin_amdgcn_mfma_f32_16x16x16f16(bfx[0], bx[tt], ai, 0, 0, 0);
      af = __builtin_amdgcn_mfma_f32_16x16x16f16(bfx[1], bx[tt], af, 0, 0, 0);
      ag = __builtin_amdgcn_mfma_f32_16x16x16f16(bfx[2], bx[tt], ag, 0, 0, 0);
      ao = __builtin_amdgcn_mfma_f32_16x16x16f16(bfx[3], bx[tt], ao, 0, 0, 0);
      __builtin_amdgcn_s_setprio(0);

      // off-critical-path staging, hidden under MFMA/act latency:
      if (tt == 0) {
        // publish chunk ch+1 into the opposite parity; the regular step
        // barrier publishes it (that parity's last reads were the chunk
        // ch-1 preload burst, >=16 barriers ago).
        union { half8 v; fp16x2 h2[4]; } P;
        P.h2[0] = __builtin_amdgcn_cvt_pkrtz(pa.x, pa.y);
        P.h2[1] = __builtin_amdgcn_cvt_pkrtz(pa.z, pa.w);
        P.h2[2] = __builtin_amdgcn_cvt_pkrtz(pb2.x, pb2.y);
        P.h2[3] = __builtin_amdgcn_cvt_pkrtz(pb2.z, pb2.w);
        *(half8*)&xlds[(ch + 1) & 1][tt_s][row_s][0] = P.v;
      }
      if (tt == 1) {
        // reissue global prefetch (chunk ch+2, wrapped); consumed 15 steps on
        const int chn = (ch + 2 < NCHUNK) ? (ch + 2) : (ch + 2 - NCHUNK);
        pa  = *(const float4*)(xps + (size_t)chn * CHUNK * INn);
        pb2 = *(const float4*)(xps + (size_t)chn * CHUNK * INn + 4);
      }

      // activations: lane's 4 elements = units u0+0..3, batch n
      const floatx2 h01 = act_pair(ai[0], ai[1], af[0], af[1],
                                   ag[0], ag[1], ao[0], ao[1], chat01);
      const floatx2 h23 = act_pair(ai[2], ai[3], af[2], af[3],
                                   ag[2], ag[3], ao[2], ao[3], chat23);

      // packed writeback: 4 consecutive units of batch n -> one b64
      union { half4 v; fp16x2 h2[2]; } Wq;
      Wq.h2[0] = __builtin_amdgcn_cvt_pkrtz(h01.x, h01.y);
      Wq.h2[1] = __builtin_amdgcn_cvt_pkrtz(h23.x, h23.y);
      *(half4*)&hbuf[pn][n][u0] = Wq.v;

      __syncthreads();
    }
  }

  // ---- epilogue: out[b] = h_T[b,:] . W_fc + b_fc   (h_T is in hbuf[0])
  if (tid < 64) {
    const int b = lane & 15;
    const int part = lane >> 4;
    float s = 0.f;
    #pragma unroll
    for (int k = 0; k < 16; ++k) {
      const int uu = part * 16 + k;
      s = __builtin_fmaf((float)hbuf[0][b][uu], W_fc[uu], s);
    }
    s += __shfl_down(s, 32);
    s += __shfl_down(s, 16);
    if (lane < 16) out[bbase + b] = s + b_fc[0];
  }
}

extern "C" void kernel_launch(void* const* d_in, const int* in_sizes, int n_in,
                              void* d_out, int out_size, void* d_ws, size_t ws_size,
                              hipStream_t stream) {
  const float* x    = (const float*)d_in[0];
  const float* W_ih = (const float*)d_in[1];
  const float* W_hh = (const float*)d_in[2];
  const float* b_ih = (const float*)d_in[3];
  const float* b_hh = (const float*)d_in[4];
  const float* W_fc = (const float*)d_in[5];
  const float* b_fc = (const float*)d_in[6];
  float* out = (float*)d_out;
  dim3 grid(Bn / BT), block(256);
  hipLaunchKernelGGL(lstm_fused, grid, block, 0, stream,
                     x, W_ih, W_hh, b_ih, b_hh, W_fc, b_fc, out);
}